// Round 4
// baseline (272.258 us; speedup 1.0000x reference)
//
#include <hip/hip_runtime.h>
#include <math.h>

#define CH 16
#define NINT 256                 // intervals
#define NPTS (NINT + 1)          // 257 samples per channel
#define TAB_ELEMS (CH * NPTS)    // 4112 floats
#define ORIGIN 8.0f              // table covers o in [-8, 8]
#define INV_H 16.0f              // 1/h, h = 16/256
#define ITERS 8                  // float4-pairs per thread, fully unrolled

// ---------------- setup kernel: build per-channel likelihood table ----------------

__device__ __forceinline__ float softplus_ref(float x) { return log1pf(expf(x)); }

__device__ float eval_net_exact(float x,
                                const float* sp0, const float* bb0, const float* tt0,
                                const float* sp1, const float* bb1, const float* tt1,
                                const float* sp2, const float* bb2, const float* tt2,
                                const float* sp3, float bb3, float tt3)
{
    float v0, v1, v2;
    {
        float l0 = fmaf(sp0[0], x, bb0[0]); v0 = fmaf(tt0[0], tanhf(l0), l0);
        float l1 = fmaf(sp0[1], x, bb0[1]); v1 = fmaf(tt0[1], tanhf(l1), l1);
        float l2 = fmaf(sp0[2], x, bb0[2]); v2 = fmaf(tt0[2], tanhf(l2), l2);
    }
    float w0, w1, w2;
    {
        float l0 = fmaf(sp1[0], v0, fmaf(sp1[1], v1, fmaf(sp1[2], v2, bb1[0])));
        float l1 = fmaf(sp1[3], v0, fmaf(sp1[4], v1, fmaf(sp1[5], v2, bb1[1])));
        float l2 = fmaf(sp1[6], v0, fmaf(sp1[7], v1, fmaf(sp1[8], v2, bb1[2])));
        w0 = fmaf(tt1[0], tanhf(l0), l0);
        w1 = fmaf(tt1[1], tanhf(l1), l1);
        w2 = fmaf(tt1[2], tanhf(l2), l2);
    }
    {
        float l0 = fmaf(sp2[0], w0, fmaf(sp2[1], w1, fmaf(sp2[2], w2, bb2[0])));
        float l1 = fmaf(sp2[3], w0, fmaf(sp2[4], w1, fmaf(sp2[5], w2, bb2[1])));
        float l2 = fmaf(sp2[6], w0, fmaf(sp2[7], w1, fmaf(sp2[8], w2, bb2[2])));
        v0 = fmaf(tt2[0], tanhf(l0), l0);
        v1 = fmaf(tt2[1], tanhf(l1), l1);
        v2 = fmaf(tt2[2], tanhf(l2), l2);
    }
    float l = fmaf(sp3[0], v0, fmaf(sp3[1], v1, fmaf(sp3[2], v2, bb3)));
    return fmaf(tt3, tanhf(l), l);
}

__global__ __launch_bounds__(256) void eb_table_kernel(
    const float* __restrict__ m0, const float* __restrict__ b0, const float* __restrict__ f0,
    const float* __restrict__ m1, const float* __restrict__ b1, const float* __restrict__ f1,
    const float* __restrict__ m2, const float* __restrict__ b2, const float* __restrict__ f2,
    const float* __restrict__ m3, const float* __restrict__ b3, const float* __restrict__ f3,
    float* __restrict__ tab)
{
    int t = blockIdx.x * blockDim.x + threadIdx.x;
    if (t >= TAB_ELEMS) return;
    int c = t / NPTS;
    int k = t - c * NPTS;

    float sp0[3], bb0[3], tt0[3];
    float sp1[9], bb1[3], tt1[3];
    float sp2[9], bb2[3], tt2[3];
    float sp3[3];
#pragma unroll
    for (int j = 0; j < 3; j++) {
        sp0[j] = softplus_ref(m0[c * 3 + j]);
        bb0[j] = b0[c * 3 + j];
        tt0[j] = tanhf(f0[c * 3 + j]);
        bb1[j] = b1[c * 3 + j];
        tt1[j] = tanhf(f1[c * 3 + j]);
        bb2[j] = b2[c * 3 + j];
        tt2[j] = tanhf(f2[c * 3 + j]);
        sp3[j] = softplus_ref(m3[c * 3 + j]);
    }
#pragma unroll
    for (int j = 0; j < 9; j++) {
        sp1[j] = softplus_ref(m1[c * 9 + j]);
        sp2[j] = softplus_ref(m2[c * 9 + j]);
    }
    float bb3 = b3[c];
    float tt3 = tanhf(f3[c]);

    float o = -ORIGIN + (float)k * (1.0f / INV_H);
    float lo = eval_net_exact(o - 0.5f, sp0, bb0, tt0, sp1, bb1, tt1, sp2, bb2, tt2, sp3, bb3, tt3);
    float up = eval_net_exact(o + 0.5f, sp0, bb0, tt0, sp1, bb1, tt1, sp2, bb2, tt2, sp3, bb3, tt3);

    float sum = lo + up;
    float s = (sum > 0.0f) ? -1.0f : ((sum < 0.0f) ? 1.0f : 0.0f);
    float su = 1.0f / (1.0f + expf(-s * up));
    float sl = 1.0f / (1.0f + expf(-s * lo));
    tab[t] = fmaxf(fabsf(su - sl), 1e-9f);
}

// ---------------- main kernel: batched unrolled stream + LDS table lerp ----------------

__device__ __forceinline__ float lookup(const float* lds, int row_base, float oe) {
    float t = fminf(fmaxf(fmaf(oe, INV_H, ORIGIN * INV_H), 0.0f), 255.999f);
    int i = (int)t;
    float fr = t - (float)i;
    const float* p = &lds[row_base + i];
    float v0 = p[0], v1 = p[1];
    return fmaxf(fmaf(fr, v1 - v0, v0), 1e-9f);
}

__global__ __launch_bounds__(256) void eb_main_kernel(
    const float4* __restrict__ inp, const float4* __restrict__ nz,
    const float* __restrict__ tab, float4* __restrict__ out, int nvec)
{
    __shared__ float lds[TAB_ELEMS];
    for (int j = threadIdx.x; j < TAB_ELEMS; j += 256) lds[j] = tab[j];

    const int tid = threadIdx.x;
    const int blockStart = blockIdx.x * (256 * ITERS);
    // chunk stride (256) and blockStart (2048*bid) are multiples of 4 ->
    // channel group is loop-invariant: c0 = (v & 3) * 4 = (tid & 3) * 4
    const int c0 = (tid & 3) * 4;
    const int r0 = (c0 + 0) * NPTS;
    const int r1 = (c0 + 1) * NPTS;
    const int r2 = (c0 + 2) * NPTS;
    const int r3 = (c0 + 3) * NPTS;

    // issue ALL global loads up-front (16 loads in flight per thread)
    float4 a[ITERS], b[ITERS];
#pragma unroll
    for (int k = 0; k < ITERS; k++) {
        int v = blockStart + k * 256 + tid;
        if (v < nvec) { a[k] = inp[v]; b[k] = nz[v]; }
    }

    __syncthreads();   // table ready

#pragma unroll
    for (int k = 0; k < ITERS; k++) {
        int v = blockStart + k * 256 + tid;
        if (v >= nvec) break;
        float4 o, lik;
        o.x = a[k].x + b[k].x - 0.5f;
        o.y = a[k].y + b[k].y - 0.5f;
        o.z = a[k].z + b[k].z - 0.5f;
        o.w = a[k].w + b[k].w - 0.5f;
        lik.x = lookup(lds, r0, o.x);
        lik.y = lookup(lds, r1, o.y);
        lik.z = lookup(lds, r2, o.z);
        lik.w = lookup(lds, r3, o.w);
        out[v] = o;
        out[nvec + v] = lik;
    }
}

// ---------------- launcher ----------------

extern "C" void kernel_launch(void* const* d_in, const int* in_sizes, int n_in,
                              void* d_out, int out_size, void* d_ws, size_t ws_size,
                              hipStream_t stream) {
    const float* inp = (const float*)d_in[0];
    const float* nz  = (const float*)d_in[1];
    const float* m0 = (const float*)d_in[2];
    const float* b0 = (const float*)d_in[3];
    const float* f0 = (const float*)d_in[4];
    const float* m1 = (const float*)d_in[5];
    const float* b1 = (const float*)d_in[6];
    const float* f1 = (const float*)d_in[7];
    const float* m2 = (const float*)d_in[8];
    const float* b2 = (const float*)d_in[9];
    const float* f2 = (const float*)d_in[10];
    const float* m3 = (const float*)d_in[11];
    const float* b3 = (const float*)d_in[12];
    const float* f3 = (const float*)d_in[13];

    float* tab = (float*)d_ws;               // 16*257 floats = 16448 B
    const int total = in_sizes[0];           // 16777216
    const int nvec = total >> 2;             // 4194304

    hipLaunchKernelGGL(eb_table_kernel, dim3((TAB_ELEMS + 255) / 256), dim3(256), 0, stream,
                       m0, b0, f0, m1, b1, f1, m2, b2, f2, m3, b3, f3, tab);

    const int chunk = 256 * ITERS;           // 2048 float4-pairs per block
    const int blocks = (nvec + chunk - 1) / chunk;   // 2048
    hipLaunchKernelGGL(eb_main_kernel, dim3(blocks), dim3(256), 0, stream,
                       (const float4*)inp, (const float4*)nz, tab, (float4*)d_out, nvec);
}

// Round 5
// 260.868 us; speedup vs baseline: 1.0437x; 1.0437x over previous
//
#include <hip/hip_runtime.h>
#include <math.h>

#define CH 16
#define NINT 256                 // intervals
#define NPTS (NINT + 1)          // 257 samples per channel
#define TAB_ELEMS (CH * NPTS)    // 4112 floats
#define ORIGIN 8.0f              // table covers o in [-8, 8]
#define INV_H 16.0f              // 1/h, h = 16/256

typedef float f32x4 __attribute__((ext_vector_type(4)));

// ---------------- setup kernel: build per-channel likelihood table ----------------

__device__ __forceinline__ float softplus_ref(float x) { return log1pf(expf(x)); }

__device__ float eval_net_exact(float x,
                                const float* sp0, const float* bb0, const float* tt0,
                                const float* sp1, const float* bb1, const float* tt1,
                                const float* sp2, const float* bb2, const float* tt2,
                                const float* sp3, float bb3, float tt3)
{
    float v0, v1, v2;
    {
        float l0 = fmaf(sp0[0], x, bb0[0]); v0 = fmaf(tt0[0], tanhf(l0), l0);
        float l1 = fmaf(sp0[1], x, bb0[1]); v1 = fmaf(tt0[1], tanhf(l1), l1);
        float l2 = fmaf(sp0[2], x, bb0[2]); v2 = fmaf(tt0[2], tanhf(l2), l2);
    }
    float w0, w1, w2;
    {
        float l0 = fmaf(sp1[0], v0, fmaf(sp1[1], v1, fmaf(sp1[2], v2, bb1[0])));
        float l1 = fmaf(sp1[3], v0, fmaf(sp1[4], v1, fmaf(sp1[5], v2, bb1[1])));
        float l2 = fmaf(sp1[6], v0, fmaf(sp1[7], v1, fmaf(sp1[8], v2, bb1[2])));
        w0 = fmaf(tt1[0], tanhf(l0), l0);
        w1 = fmaf(tt1[1], tanhf(l1), l1);
        w2 = fmaf(tt1[2], tanhf(l2), l2);
    }
    {
        float l0 = fmaf(sp2[0], w0, fmaf(sp2[1], w1, fmaf(sp2[2], w2, bb2[0])));
        float l1 = fmaf(sp2[3], w0, fmaf(sp2[4], w1, fmaf(sp2[5], w2, bb2[1])));
        float l2 = fmaf(sp2[6], w0, fmaf(sp2[7], w1, fmaf(sp2[8], w2, bb2[2])));
        v0 = fmaf(tt2[0], tanhf(l0), l0);
        v1 = fmaf(tt2[1], tanhf(l1), l1);
        v2 = fmaf(tt2[2], tanhf(l2), l2);
    }
    float l = fmaf(sp3[0], v0, fmaf(sp3[1], v1, fmaf(sp3[2], v2, bb3)));
    return fmaf(tt3, tanhf(l), l);
}

__global__ __launch_bounds__(256) void eb_table_kernel(
    const float* __restrict__ m0, const float* __restrict__ b0, const float* __restrict__ f0,
    const float* __restrict__ m1, const float* __restrict__ b1, const float* __restrict__ f1,
    const float* __restrict__ m2, const float* __restrict__ b2, const float* __restrict__ f2,
    const float* __restrict__ m3, const float* __restrict__ b3, const float* __restrict__ f3,
    float* __restrict__ tab)
{
    int t = blockIdx.x * blockDim.x + threadIdx.x;
    if (t >= TAB_ELEMS) return;
    int c = t / NPTS;
    int k = t - c * NPTS;

    float sp0[3], bb0[3], tt0[3];
    float sp1[9], bb1[3], tt1[3];
    float sp2[9], bb2[3], tt2[3];
    float sp3[3];
#pragma unroll
    for (int j = 0; j < 3; j++) {
        sp0[j] = softplus_ref(m0[c * 3 + j]);
        bb0[j] = b0[c * 3 + j];
        tt0[j] = tanhf(f0[c * 3 + j]);
        bb1[j] = b1[c * 3 + j];
        tt1[j] = tanhf(f1[c * 3 + j]);
        bb2[j] = b2[c * 3 + j];
        tt2[j] = tanhf(f2[c * 3 + j]);
        sp3[j] = softplus_ref(m3[c * 3 + j]);
    }
#pragma unroll
    for (int j = 0; j < 9; j++) {
        sp1[j] = softplus_ref(m1[c * 9 + j]);
        sp2[j] = softplus_ref(m2[c * 9 + j]);
    }
    float bb3 = b3[c];
    float tt3 = tanhf(f3[c]);

    float o = -ORIGIN + (float)k * (1.0f / INV_H);
    float lo = eval_net_exact(o - 0.5f, sp0, bb0, tt0, sp1, bb1, tt1, sp2, bb2, tt2, sp3, bb3, tt3);
    float up = eval_net_exact(o + 0.5f, sp0, bb0, tt0, sp1, bb1, tt1, sp2, bb2, tt2, sp3, bb3, tt3);

    float sum = lo + up;
    float s = (sum > 0.0f) ? -1.0f : ((sum < 0.0f) ? 1.0f : 0.0f);
    float su = 1.0f / (1.0f + expf(-s * up));
    float sl = 1.0f / (1.0f + expf(-s * lo));
    tab[t] = fmaxf(fabsf(su - sl), 1e-9f);
}

// ---------------- main kernel: grid-stride stream + LDS table lerp, NT cache hints ----------------

__device__ __forceinline__ float lookup(const float* lds, int row_base, float oe) {
    float t = fminf(fmaxf(fmaf(oe, INV_H, ORIGIN * INV_H), 0.0f), 255.999f);
    int i = (int)t;
    float fr = t - (float)i;
    const float* p = &lds[row_base + i];
    float v0 = p[0], v1 = p[1];
    return fmaxf(fmaf(fr, v1 - v0, v0), 1e-9f);
}

__global__ __launch_bounds__(256) void eb_main_kernel(
    const f32x4* __restrict__ inp, const f32x4* __restrict__ nz,
    const float* __restrict__ tab, f32x4* __restrict__ out, int nvec)
{
    __shared__ float lds[TAB_ELEMS];
    for (int j = threadIdx.x; j < TAB_ELEMS; j += 256) lds[j] = tab[j];
    __syncthreads();

    const int gtid = blockIdx.x * 256 + threadIdx.x;
    const int stride = gridDim.x * 256;
    // stride and gtid-base are multiples of 4 -> channel group loop-invariant
    const int c0 = (gtid & 3) * 4;
    const int r0 = (c0 + 0) * NPTS;
    const int r1 = (c0 + 1) * NPTS;
    const int r2 = (c0 + 2) * NPTS;
    const int r3 = (c0 + 3) * NPTS;

    for (int v = gtid; v < nvec; v += stride) {
        f32x4 a = __builtin_nontemporal_load(&inp[v]);
        f32x4 b = __builtin_nontemporal_load(&nz[v]);

        f32x4 o, lik;
        o.x = a.x + b.x - 0.5f;
        o.y = a.y + b.y - 0.5f;
        o.z = a.z + b.z - 0.5f;
        o.w = a.w + b.w - 0.5f;
        lik.x = lookup(lds, r0, o.x);
        lik.y = lookup(lds, r1, o.y);
        lik.z = lookup(lds, r2, o.z);
        lik.w = lookup(lds, r3, o.w);

        __builtin_nontemporal_store(o, &out[v]);
        __builtin_nontemporal_store(lik, &out[nvec + v]);
    }
}

// ---------------- launcher ----------------

extern "C" void kernel_launch(void* const* d_in, const int* in_sizes, int n_in,
                              void* d_out, int out_size, void* d_ws, size_t ws_size,
                              hipStream_t stream) {
    const float* inp = (const float*)d_in[0];
    const float* nz  = (const float*)d_in[1];
    const float* m0 = (const float*)d_in[2];
    const float* b0 = (const float*)d_in[3];
    const float* f0 = (const float*)d_in[4];
    const float* m1 = (const float*)d_in[5];
    const float* b1 = (const float*)d_in[6];
    const float* f1 = (const float*)d_in[7];
    const float* m2 = (const float*)d_in[8];
    const float* b2 = (const float*)d_in[9];
    const float* f2 = (const float*)d_in[10];
    const float* m3 = (const float*)d_in[11];
    const float* b3 = (const float*)d_in[12];
    const float* f3 = (const float*)d_in[13];

    float* tab = (float*)d_ws;               // 16*257 floats = 16448 B
    const int total = in_sizes[0];           // 16777216
    const int nvec = total >> 2;             // 4194304

    hipLaunchKernelGGL(eb_table_kernel, dim3((TAB_ELEMS + 255) / 256), dim3(256), 0, stream,
                       m0, b0, f0, m1, b1, f1, m2, b2, f2, m3, b3, f3, tab);

    hipLaunchKernelGGL(eb_main_kernel, dim3(2048), dim3(256), 0, stream,
                       (const f32x4*)inp, (const f32x4*)nz, tab, (f32x4*)d_out, nvec);
}

// Round 6
// 258.540 us; speedup vs baseline: 1.0531x; 1.0090x over previous
//
#include <hip/hip_runtime.h>
#include <math.h>

#define CH 16
#define NINT 256                 // intervals
#define NPTS (NINT + 1)          // 257 samples per channel
#define TAB_ELEMS (CH * NPTS)    // 4112 floats
#define ORIGIN 8.0f              // table covers o in [-8, 8]
#define INV_H 16.0f              // 1/h, h = 16/256
#define TPB 512                  // threads per block (fast path)
#define NITER 8                  // iterations per thread (fast path)

typedef float f32x4 __attribute__((ext_vector_type(4)));

// ---------------- setup kernel: build per-channel likelihood table ----------------

__device__ __forceinline__ float softplus_ref(float x) { return log1pf(expf(x)); }

__device__ float eval_net_exact(float x,
                                const float* sp0, const float* bb0, const float* tt0,
                                const float* sp1, const float* bb1, const float* tt1,
                                const float* sp2, const float* bb2, const float* tt2,
                                const float* sp3, float bb3, float tt3)
{
    float v0, v1, v2;
    {
        float l0 = fmaf(sp0[0], x, bb0[0]); v0 = fmaf(tt0[0], tanhf(l0), l0);
        float l1 = fmaf(sp0[1], x, bb0[1]); v1 = fmaf(tt0[1], tanhf(l1), l1);
        float l2 = fmaf(sp0[2], x, bb0[2]); v2 = fmaf(tt0[2], tanhf(l2), l2);
    }
    float w0, w1, w2;
    {
        float l0 = fmaf(sp1[0], v0, fmaf(sp1[1], v1, fmaf(sp1[2], v2, bb1[0])));
        float l1 = fmaf(sp1[3], v0, fmaf(sp1[4], v1, fmaf(sp1[5], v2, bb1[1])));
        float l2 = fmaf(sp1[6], v0, fmaf(sp1[7], v1, fmaf(sp1[8], v2, bb1[2])));
        w0 = fmaf(tt1[0], tanhf(l0), l0);
        w1 = fmaf(tt1[1], tanhf(l1), l1);
        w2 = fmaf(tt1[2], tanhf(l2), l2);
    }
    {
        float l0 = fmaf(sp2[0], w0, fmaf(sp2[1], w1, fmaf(sp2[2], w2, bb2[0])));
        float l1 = fmaf(sp2[3], w0, fmaf(sp2[4], w1, fmaf(sp2[5], w2, bb2[1])));
        float l2 = fmaf(sp2[6], w0, fmaf(sp2[7], w1, fmaf(sp2[8], w2, bb2[2])));
        v0 = fmaf(tt2[0], tanhf(l0), l0);
        v1 = fmaf(tt2[1], tanhf(l1), l1);
        v2 = fmaf(tt2[2], tanhf(l2), l2);
    }
    float l = fmaf(sp3[0], v0, fmaf(sp3[1], v1, fmaf(sp3[2], v2, bb3)));
    return fmaf(tt3, tanhf(l), l);
}

__global__ __launch_bounds__(256) void eb_table_kernel(
    const float* __restrict__ m0, const float* __restrict__ b0, const float* __restrict__ f0,
    const float* __restrict__ m1, const float* __restrict__ b1, const float* __restrict__ f1,
    const float* __restrict__ m2, const float* __restrict__ b2, const float* __restrict__ f2,
    const float* __restrict__ m3, const float* __restrict__ b3, const float* __restrict__ f3,
    float* __restrict__ tab)
{
    int t = blockIdx.x * blockDim.x + threadIdx.x;
    if (t >= TAB_ELEMS) return;
    int c = t / NPTS;
    int k = t - c * NPTS;

    float sp0[3], bb0[3], tt0[3];
    float sp1[9], bb1[3], tt1[3];
    float sp2[9], bb2[3], tt2[3];
    float sp3[3];
#pragma unroll
    for (int j = 0; j < 3; j++) {
        sp0[j] = softplus_ref(m0[c * 3 + j]);
        bb0[j] = b0[c * 3 + j];
        tt0[j] = tanhf(f0[c * 3 + j]);
        bb1[j] = b1[c * 3 + j];
        tt1[j] = tanhf(f1[c * 3 + j]);
        bb2[j] = b2[c * 3 + j];
        tt2[j] = tanhf(f2[c * 3 + j]);
        sp3[j] = softplus_ref(m3[c * 3 + j]);
    }
#pragma unroll
    for (int j = 0; j < 9; j++) {
        sp1[j] = softplus_ref(m1[c * 9 + j]);
        sp2[j] = softplus_ref(m2[c * 9 + j]);
    }
    float bb3 = b3[c];
    float tt3 = tanhf(f3[c]);

    float o = -ORIGIN + (float)k * (1.0f / INV_H);
    float lo = eval_net_exact(o - 0.5f, sp0, bb0, tt0, sp1, bb1, tt1, sp2, bb2, tt2, sp3, bb3, tt3);
    float up = eval_net_exact(o + 0.5f, sp0, bb0, tt0, sp1, bb1, tt1, sp2, bb2, tt2, sp3, bb3, tt3);

    float sum = lo + up;
    float s = (sum > 0.0f) ? -1.0f : ((sum < 0.0f) ? 1.0f : 0.0f);
    float su = 1.0f / (1.0f + expf(-s * up));
    float sl = 1.0f / (1.0f + expf(-s * lo));
    tab[t] = fmaxf(fabsf(su - sl), 1e-9f);
}

// ---------------- main kernels ----------------

__device__ __forceinline__ float lookup(const float* lds, int row_base, float oe) {
    float t = fminf(fmaxf(fmaf(oe, INV_H, ORIGIN * INV_H), 0.0f), 255.999f);
    int i = (int)t;
    float fr = t - (float)i;
    const float* p = &lds[row_base + i];
    float v0 = p[0], v1 = p[1];
    return fmaxf(fmaf(fr, v1 - v0, v0), 1e-9f);
}

// fast path: nvec == TPB * NITER * gridDim.x exactly -> no guards, full unroll
__global__ __launch_bounds__(TPB) void eb_main_exact(
    const f32x4* __restrict__ inp, const f32x4* __restrict__ nz,
    const float* __restrict__ tab, f32x4* __restrict__ out, int nvec)
{
    __shared__ float lds[TAB_ELEMS];
    for (int j = threadIdx.x; j < TAB_ELEMS; j += TPB) lds[j] = tab[j];
    __syncthreads();

    const int gtid = blockIdx.x * TPB + threadIdx.x;
    const int stride = gridDim.x * TPB;        // multiple of 4
    const int c0 = (gtid & 3) * 4;
    const int r0 = (c0 + 0) * NPTS;
    const int r1 = (c0 + 1) * NPTS;
    const int r2 = (c0 + 2) * NPTS;
    const int r3 = (c0 + 3) * NPTS;

#pragma unroll
    for (int kk = 0; kk < NITER; kk += 4) {
        // group of 4 independent iterations: loads hoistable, no guards
        f32x4 a[4], b[4];
#pragma unroll
        for (int u = 0; u < 4; u++) {
            int v = gtid + (kk + u) * stride;
            a[u] = __builtin_nontemporal_load(&inp[v]);
            b[u] = __builtin_nontemporal_load(&nz[v]);
        }
#pragma unroll
        for (int u = 0; u < 4; u++) {
            int v = gtid + (kk + u) * stride;
            f32x4 o, lik;
            o.x = a[u].x + b[u].x - 0.5f;
            o.y = a[u].y + b[u].y - 0.5f;
            o.z = a[u].z + b[u].z - 0.5f;
            o.w = a[u].w + b[u].w - 0.5f;
            lik.x = lookup(lds, r0, o.x);
            lik.y = lookup(lds, r1, o.y);
            lik.z = lookup(lds, r2, o.z);
            lik.w = lookup(lds, r3, o.w);
            __builtin_nontemporal_store(o, &out[v]);
            __builtin_nontemporal_store(lik, &out[nvec + v]);
        }
    }
}

// fallback: guarded grid-stride (any size)
__global__ __launch_bounds__(256) void eb_main_generic(
    const f32x4* __restrict__ inp, const f32x4* __restrict__ nz,
    const float* __restrict__ tab, f32x4* __restrict__ out, int nvec)
{
    __shared__ float lds[TAB_ELEMS];
    for (int j = threadIdx.x; j < TAB_ELEMS; j += 256) lds[j] = tab[j];
    __syncthreads();

    const int gtid = blockIdx.x * 256 + threadIdx.x;
    const int stride = gridDim.x * 256;
    const int c0 = (gtid & 3) * 4;
    const int r0 = (c0 + 0) * NPTS;
    const int r1 = (c0 + 1) * NPTS;
    const int r2 = (c0 + 2) * NPTS;
    const int r3 = (c0 + 3) * NPTS;

    for (int v = gtid; v < nvec; v += stride) {
        f32x4 a = __builtin_nontemporal_load(&inp[v]);
        f32x4 b = __builtin_nontemporal_load(&nz[v]);
        f32x4 o, lik;
        o.x = a.x + b.x - 0.5f;
        o.y = a.y + b.y - 0.5f;
        o.z = a.z + b.z - 0.5f;
        o.w = a.w + b.w - 0.5f;
        lik.x = lookup(lds, r0, o.x);
        lik.y = lookup(lds, r1, o.y);
        lik.z = lookup(lds, r2, o.z);
        lik.w = lookup(lds, r3, o.w);
        __builtin_nontemporal_store(o, &out[v]);
        __builtin_nontemporal_store(lik, &out[nvec + v]);
    }
}

// ---------------- launcher ----------------

extern "C" void kernel_launch(void* const* d_in, const int* in_sizes, int n_in,
                              void* d_out, int out_size, void* d_ws, size_t ws_size,
                              hipStream_t stream) {
    const float* inp = (const float*)d_in[0];
    const float* nz  = (const float*)d_in[1];
    const float* m0 = (const float*)d_in[2];
    const float* b0 = (const float*)d_in[3];
    const float* f0 = (const float*)d_in[4];
    const float* m1 = (const float*)d_in[5];
    const float* b1 = (const float*)d_in[6];
    const float* f1 = (const float*)d_in[7];
    const float* m2 = (const float*)d_in[8];
    const float* b2 = (const float*)d_in[9];
    const float* f2 = (const float*)d_in[10];
    const float* m3 = (const float*)d_in[11];
    const float* b3 = (const float*)d_in[12];
    const float* f3 = (const float*)d_in[13];

    float* tab = (float*)d_ws;               // 16*257 floats = 16448 B
    const int total = in_sizes[0];           // 16777216
    const int nvec = total >> 2;             // 4194304

    hipLaunchKernelGGL(eb_table_kernel, dim3((TAB_ELEMS + 255) / 256), dim3(256), 0, stream,
                       m0, b0, f0, m1, b1, f1, m2, b2, f2, m3, b3, f3, tab);

    const int chunk = TPB * NITER;                       // 4096
    if (nvec % chunk == 0) {
        hipLaunchKernelGGL(eb_main_exact, dim3(nvec / chunk), dim3(TPB), 0, stream,
                           (const f32x4*)inp, (const f32x4*)nz, tab, (f32x4*)d_out, nvec);
    } else {
        hipLaunchKernelGGL(eb_main_generic, dim3(2048), dim3(256), 0, stream,
                           (const f32x4*)inp, (const f32x4*)nz, tab, (f32x4*)d_out, nvec);
    }
}

// Round 7
// 255.446 us; speedup vs baseline: 1.0658x; 1.0121x over previous
//
#include <hip/hip_runtime.h>
#include <math.h>

#define CH 16
#define NINT 256                 // intervals
#define NPTS (NINT + 1)          // 257 samples per channel
#define TAB_ELEMS (CH * NPTS)    // 4112 floats
#define ORIGIN 8.0f              // table covers o in [-8, 8]
#define INV_H 16.0f              // 1/h, h = 16/256
#define TPB 512                  // threads per block (fast path)
#define NITER 4                  // float4-pairs per thread (fast path)

typedef float f32x4 __attribute__((ext_vector_type(4)));

// ---------------- setup kernel: build per-channel likelihood table ----------------

__device__ __forceinline__ float softplus_ref(float x) { return log1pf(expf(x)); }

__device__ float eval_net_exact(float x,
                                const float* sp0, const float* bb0, const float* tt0,
                                const float* sp1, const float* bb1, const float* tt1,
                                const float* sp2, const float* bb2, const float* tt2,
                                const float* sp3, float bb3, float tt3)
{
    float v0, v1, v2;
    {
        float l0 = fmaf(sp0[0], x, bb0[0]); v0 = fmaf(tt0[0], tanhf(l0), l0);
        float l1 = fmaf(sp0[1], x, bb0[1]); v1 = fmaf(tt0[1], tanhf(l1), l1);
        float l2 = fmaf(sp0[2], x, bb0[2]); v2 = fmaf(tt0[2], tanhf(l2), l2);
    }
    float w0, w1, w2;
    {
        float l0 = fmaf(sp1[0], v0, fmaf(sp1[1], v1, fmaf(sp1[2], v2, bb1[0])));
        float l1 = fmaf(sp1[3], v0, fmaf(sp1[4], v1, fmaf(sp1[5], v2, bb1[1])));
        float l2 = fmaf(sp1[6], v0, fmaf(sp1[7], v1, fmaf(sp1[8], v2, bb1[2])));
        w0 = fmaf(tt1[0], tanhf(l0), l0);
        w1 = fmaf(tt1[1], tanhf(l1), l1);
        w2 = fmaf(tt1[2], tanhf(l2), l2);
    }
    {
        float l0 = fmaf(sp2[0], w0, fmaf(sp2[1], w1, fmaf(sp2[2], w2, bb2[0])));
        float l1 = fmaf(sp2[3], w0, fmaf(sp2[4], w1, fmaf(sp2[5], w2, bb2[1])));
        float l2 = fmaf(sp2[6], w0, fmaf(sp2[7], w1, fmaf(sp2[8], w2, bb2[2])));
        v0 = fmaf(tt2[0], tanhf(l0), l0);
        v1 = fmaf(tt2[1], tanhf(l1), l1);
        v2 = fmaf(tt2[2], tanhf(l2), l2);
    }
    float l = fmaf(sp3[0], v0, fmaf(sp3[1], v1, fmaf(sp3[2], v2, bb3)));
    return fmaf(tt3, tanhf(l), l);
}

__global__ __launch_bounds__(256) void eb_table_kernel(
    const float* __restrict__ m0, const float* __restrict__ b0, const float* __restrict__ f0,
    const float* __restrict__ m1, const float* __restrict__ b1, const float* __restrict__ f1,
    const float* __restrict__ m2, const float* __restrict__ b2, const float* __restrict__ f2,
    const float* __restrict__ m3, const float* __restrict__ b3, const float* __restrict__ f3,
    float* __restrict__ tab)
{
    int t = blockIdx.x * blockDim.x + threadIdx.x;
    if (t >= TAB_ELEMS) return;
    int c = t / NPTS;
    int k = t - c * NPTS;

    float sp0[3], bb0[3], tt0[3];
    float sp1[9], bb1[3], tt1[3];
    float sp2[9], bb2[3], tt2[3];
    float sp3[3];
#pragma unroll
    for (int j = 0; j < 3; j++) {
        sp0[j] = softplus_ref(m0[c * 3 + j]);
        bb0[j] = b0[c * 3 + j];
        tt0[j] = tanhf(f0[c * 3 + j]);
        bb1[j] = b1[c * 3 + j];
        tt1[j] = tanhf(f1[c * 3 + j]);
        bb2[j] = b2[c * 3 + j];
        tt2[j] = tanhf(f2[c * 3 + j]);
        sp3[j] = softplus_ref(m3[c * 3 + j]);
    }
#pragma unroll
    for (int j = 0; j < 9; j++) {
        sp1[j] = softplus_ref(m1[c * 9 + j]);
        sp2[j] = softplus_ref(m2[c * 9 + j]);
    }
    float bb3 = b3[c];
    float tt3 = tanhf(f3[c]);

    float o = -ORIGIN + (float)k * (1.0f / INV_H);
    float lo = eval_net_exact(o - 0.5f, sp0, bb0, tt0, sp1, bb1, tt1, sp2, bb2, tt2, sp3, bb3, tt3);
    float up = eval_net_exact(o + 0.5f, sp0, bb0, tt0, sp1, bb1, tt1, sp2, bb2, tt2, sp3, bb3, tt3);

    float sum = lo + up;
    float s = (sum > 0.0f) ? -1.0f : ((sum < 0.0f) ? 1.0f : 0.0f);
    float su = 1.0f / (1.0f + expf(-s * up));
    float sl = 1.0f / (1.0f + expf(-s * lo));
    tab[t] = fmaxf(fabsf(su - sl), 1e-9f);
}

// ---------------- main kernels ----------------

__device__ __forceinline__ float lookup(const float* lds, int row_base, float oe) {
    float t = fminf(fmaxf(fmaf(oe, INV_H, ORIGIN * INV_H), 0.0f), 255.999f);
    int i = (int)t;
    float fr = t - (float)i;
    const float* p = &lds[row_base + i];
    float v0 = p[0], v1 = p[1];
    return fmaxf(fmaf(fr, v1 - v0, v0), 1e-9f);
}

// fast path: nvec == TPB * NITER * gridDim.x exactly.
// Three phases, NO guards: (1) issue all global loads, (2) stage table + sync,
// (3) compute + NT stores. No store precedes any load in program order, so
// in-order vmcnt retirement never makes a load-wait depend on store drain.
__global__ __launch_bounds__(TPB) void eb_main_exact(
    const f32x4* __restrict__ inp, const f32x4* __restrict__ nz,
    const float* __restrict__ tab, f32x4* __restrict__ out, int nvec)
{
    __shared__ float lds[TAB_ELEMS];

    const int tid = threadIdx.x;
    const int base = blockIdx.x * (TPB * NITER) + tid;   // block-contiguous chunk
    // TPB and base-offset are multiples of 4 -> channel group invariant
    const int c0 = (tid & 3) * 4;
    const int r0 = (c0 + 0) * NPTS;
    const int r1 = (c0 + 1) * NPTS;
    const int r2 = (c0 + 2) * NPTS;
    const int r3 = (c0 + 3) * NPTS;

    // phase 1: all input loads in flight (8 per thread)
    f32x4 a[NITER], b[NITER];
#pragma unroll
    for (int u = 0; u < NITER; u++) {
        a[u] = __builtin_nontemporal_load(&inp[base + u * TPB]);
        b[u] = __builtin_nontemporal_load(&nz[base + u * TPB]);
    }

    // phase 2: table staging overlaps the input-load latency
    for (int j = tid; j < TAB_ELEMS; j += TPB) lds[j] = tab[j];
    __syncthreads();

    // phase 3: compute + stores
#pragma unroll
    for (int u = 0; u < NITER; u++) {
        const int v = base + u * TPB;
        f32x4 o, lik;
        o.x = a[u].x + b[u].x - 0.5f;
        o.y = a[u].y + b[u].y - 0.5f;
        o.z = a[u].z + b[u].z - 0.5f;
        o.w = a[u].w + b[u].w - 0.5f;
        lik.x = lookup(lds, r0, o.x);
        lik.y = lookup(lds, r1, o.y);
        lik.z = lookup(lds, r2, o.z);
        lik.w = lookup(lds, r3, o.w);
        __builtin_nontemporal_store(o, &out[v]);
        __builtin_nontemporal_store(lik, &out[nvec + v]);
    }
}

// fallback: guarded grid-stride (any size)
__global__ __launch_bounds__(256) void eb_main_generic(
    const f32x4* __restrict__ inp, const f32x4* __restrict__ nz,
    const float* __restrict__ tab, f32x4* __restrict__ out, int nvec)
{
    __shared__ float lds[TAB_ELEMS];
    for (int j = threadIdx.x; j < TAB_ELEMS; j += 256) lds[j] = tab[j];
    __syncthreads();

    const int gtid = blockIdx.x * 256 + threadIdx.x;
    const int stride = gridDim.x * 256;
    const int c0 = (gtid & 3) * 4;
    const int r0 = (c0 + 0) * NPTS;
    const int r1 = (c0 + 1) * NPTS;
    const int r2 = (c0 + 2) * NPTS;
    const int r3 = (c0 + 3) * NPTS;

    for (int v = gtid; v < nvec; v += stride) {
        f32x4 a = __builtin_nontemporal_load(&inp[v]);
        f32x4 b = __builtin_nontemporal_load(&nz[v]);
        f32x4 o, lik;
        o.x = a.x + b.x - 0.5f;
        o.y = a.y + b.y - 0.5f;
        o.z = a.z + b.z - 0.5f;
        o.w = a.w + b.w - 0.5f;
        lik.x = lookup(lds, r0, o.x);
        lik.y = lookup(lds, r1, o.y);
        lik.z = lookup(lds, r2, o.z);
        lik.w = lookup(lds, r3, o.w);
        __builtin_nontemporal_store(o, &out[v]);
        __builtin_nontemporal_store(lik, &out[nvec + v]);
    }
}

// ---------------- launcher ----------------

extern "C" void kernel_launch(void* const* d_in, const int* in_sizes, int n_in,
                              void* d_out, int out_size, void* d_ws, size_t ws_size,
                              hipStream_t stream) {
    const float* inp = (const float*)d_in[0];
    const float* nz  = (const float*)d_in[1];
    const float* m0 = (const float*)d_in[2];
    const float* b0 = (const float*)d_in[3];
    const float* f0 = (const float*)d_in[4];
    const float* m1 = (const float*)d_in[5];
    const float* b1 = (const float*)d_in[6];
    const float* f1 = (const float*)d_in[7];
    const float* m2 = (const float*)d_in[8];
    const float* b2 = (const float*)d_in[9];
    const float* f2 = (const float*)d_in[10];
    const float* m3 = (const float*)d_in[11];
    const float* b3 = (const float*)d_in[12];
    const float* f3 = (const float*)d_in[13];

    float* tab = (float*)d_ws;               // 16*257 floats = 16448 B
    const int total = in_sizes[0];           // 16777216
    const int nvec = total >> 2;             // 4194304

    hipLaunchKernelGGL(eb_table_kernel, dim3((TAB_ELEMS + 255) / 256), dim3(256), 0, stream,
                       m0, b0, f0, m1, b1, f1, m2, b2, f2, m3, b3, f3, tab);

    const int chunk = TPB * NITER;                       // 2048
    if (nvec % chunk == 0) {
        hipLaunchKernelGGL(eb_main_exact, dim3(nvec / chunk), dim3(TPB), 0, stream,
                           (const f32x4*)inp, (const f32x4*)nz, tab, (f32x4*)d_out, nvec);
    } else {
        hipLaunchKernelGGL(eb_main_generic, dim3(2048), dim3(256), 0, stream,
                           (const f32x4*)inp, (const f32x4*)nz, tab, (f32x4*)d_out, nvec);
    }
}